// Round 7
// baseline (171.211 us; speedup 1.0000x reference)
//
#include <hip/hip_runtime.h>
#include <math.h>
#include <stdint.h>

typedef short bf16x8 __attribute__((ext_vector_type(8)));
typedef float f32x16 __attribute__((ext_vector_type(16)));
typedef unsigned short ushort_t;

// ---------------- workspace layout ----------------
// floats: part[32][32][64] @0, cin @65536, cout @67584, sp9 @69632, k4 @69920
// bytes:  wfb @ 294912 (2.36 MB), xb @ 2654208 (64 MiB)  -> total 69.76 MB
#define WP_PART 0
#define WP_CIN  65536
#define WP_COUT 67584
#define WP_SP9  69632
#define WP_K4   69920
#define WB_WFB  294912
#define WB_XB   2654208

static __device__ __forceinline__ unsigned f2bf(float f) {
  unsigned u = __builtin_bit_cast(unsigned, f);
  return (u + 0x7FFFu + ((u >> 16) & 1u)) >> 16;   // RNE
}
static __device__ __forceinline__ unsigned pk2(float a, float b) {
  return f2bf(a) | (f2bf(b) << 16);
}

// ---------------- 1) convert+pool: fp32 NCHW -> bf16 NHWC, pool partials ----------------
// block: (b, band of 4 rows); 256 thr. thread: ci-pair (t&31), px segment (t>>5)*16.
__global__ __launch_bounds__(256) void convert_kernel(const float* __restrict__ x,
                                                      ushort_t* __restrict__ xb,
                                                      float* __restrict__ part) {
  const int b    = blockIdx.x >> 5;
  const int band = blockIdx.x & 31;
  const int r0   = band << 2;
  const int t    = threadIdx.x;
  const int cp   = t & 31;
  const int seg  = t >> 5;

  __shared__ __align__(16) ushort_t tile[128 * 64];   // 16 KB [px][ci]
  __shared__ float red[512];

  float sa = 0.f, sb = 0.f;
  const float* xa  = x + ((size_t)(b * 64 + 2 * cp) * 16384);
  const float* xb_ = xa + 16384;

  for (int r = 0; r < 4; ++r) {
    const int gr = r0 + r;
    const int p0 = gr * 128 + seg * 16;
    float4 a0 = *(const float4*)(xa + p0);
    float4 a1 = *(const float4*)(xa + p0 + 4);
    float4 a2 = *(const float4*)(xa + p0 + 8);
    float4 a3 = *(const float4*)(xa + p0 + 12);
    float4 b0 = *(const float4*)(xb_ + p0);
    float4 b1 = *(const float4*)(xb_ + p0 + 4);
    float4 b2 = *(const float4*)(xb_ + p0 + 8);
    float4 b3 = *(const float4*)(xb_ + p0 + 12);
    sa += (a0.x + a0.y + a0.z + a0.w) + (a1.x + a1.y + a1.z + a1.w) +
          (a2.x + a2.y + a2.z + a2.w) + (a3.x + a3.y + a3.z + a3.w);
    sb += (b0.x + b0.y + b0.z + b0.w) + (b1.x + b1.y + b1.z + b1.w) +
          (b2.x + b2.y + b2.z + b2.w) + (b3.x + b3.y + b3.z + b3.w);

    unsigned* tp = (unsigned*)tile;
    const int base = seg * 16 * 32 + cp;        // uint index px*32 + cp
    tp[base +  0 * 32] = pk2(a0.x, b0.x);
    tp[base +  1 * 32] = pk2(a0.y, b0.y);
    tp[base +  2 * 32] = pk2(a0.z, b0.z);
    tp[base +  3 * 32] = pk2(a0.w, b0.w);
    tp[base +  4 * 32] = pk2(a1.x, b1.x);
    tp[base +  5 * 32] = pk2(a1.y, b1.y);
    tp[base +  6 * 32] = pk2(a1.z, b1.z);
    tp[base +  7 * 32] = pk2(a1.w, b1.w);
    tp[base +  8 * 32] = pk2(a2.x, b2.x);
    tp[base +  9 * 32] = pk2(a2.y, b2.y);
    tp[base + 10 * 32] = pk2(a2.z, b2.z);
    tp[base + 11 * 32] = pk2(a2.w, b2.w);
    tp[base + 12 * 32] = pk2(a3.x, b3.x);
    tp[base + 13 * 32] = pk2(a3.y, b3.y);
    tp[base + 14 * 32] = pk2(a3.z, b3.z);
    tp[base + 15 * 32] = pk2(a3.w, b3.w);
    __syncthreads();

    ushort_t* xbr = xb + ((size_t)(b * 16384 + gr * 128)) * 64;
#pragma unroll
    for (int i = 0; i < 4; ++i) {
      const int s = i * 256 + t;                 // px = s>>3, oct = s&7
      uint4 v = *(const uint4*)((const char*)tile + s * 16);
      *(uint4*)(xbr + (size_t)s * 8) = v;
    }
    __syncthreads();
  }

  red[t] = sa;
  red[256 + t] = sb;
  __syncthreads();
  if (t < 64) {
    const int ci = t;
    const int base = (ci & 1) * 256 + (ci >> 1);
    float s = 0.f;
#pragma unroll
    for (int k = 0; k < 8; ++k) s += red[base + k * 32];
    part[((size_t)b * 32 + band) * 64 + ci] = s;
  }
}

// ---------------- 2) attention chain, one block per batch ----------------
__global__ __launch_bounds__(128) void att_kernel(
    const float* __restrict__ pin, int n_part,
    const float* __restrict__ fc_w, const float* __restrict__ ch_w, const float* __restrict__ ch_b,
    const float* __restrict__ f_w,  const float* __restrict__ f_b,
    const float* __restrict__ sp_w, const float* __restrict__ sp_b,
    const float* __restrict__ k_w,  const float* __restrict__ k_b,
    const float* __restrict__ fus_w1, const float* __restrict__ fus_b1,
    const float* __restrict__ fus_w2, const float* __restrict__ fus_b2,
    float* __restrict__ o_cin, float* __restrict__ o_cout,
    float* __restrict__ o_sp9, float* __restrict__ o_k4) {
  const int b = blockIdx.x;
  const int t = threadIdx.x;
  __shared__ float s_pool[64], s_a[16], s_att[128], s_sp[9], s_k[4], s_h[8],
      s_att2[128], s_red[2], s_w12[2];

  if (t < 64) {
    float s = 0.f;
    for (int g = 0; g < n_part; ++g) s += pin[((size_t)b * n_part + g) * 64 + t];
    s_pool[t] = s * (1.f / 16384.f);
  }
  __syncthreads();

  if (t < 16) {
    float s = 0.f;
    for (int c = 0; c < 64; ++c) s += s_pool[c] * fc_w[t * 64 + c];
    s_a[t] = fmaxf(s, 0.f);
  }
  __syncthreads();

  if (t < 64) {
    float s = ch_b[t];
    for (int j = 0; j < 16; ++j) s += s_a[j] * ch_w[t * 16 + j];
    s_att[t] = 1.f / (1.f + expf(-s));
  } else {
    const int o = t - 64;
    float s = f_b[o];
    for (int j = 0; j < 16; ++j) s += s_a[j] * f_w[o * 16 + j];
    s_att[t] = 1.f / (1.f + expf(-s));
  }
  if (t < 9) {
    float s = sp_b[t];
    for (int j = 0; j < 16; ++j) s += s_a[j] * sp_w[t * 16 + j];
    s_sp[t] = 1.f / (1.f + expf(-s));
  }
  if (t < 4) {
    float s = k_b[t];
    for (int j = 0; j < 16; ++j) s += s_a[j] * k_w[t * 16 + j];
    s_k[t] = s;
  }
  __syncthreads();

  if (t < 8) {
    float s = fus_b1[t];
    for (int c = 0; c < 128; ++c) s += s_att[c] * fus_w1[t * 128 + c];
    s_h[t] = fmaxf(s, 0.f);
  }
  if (t == 127) {
    float m = fmaxf(fmaxf(s_k[0], s_k[1]), fmaxf(s_k[2], s_k[3]));
    float e0 = expf(s_k[0] - m), e1 = expf(s_k[1] - m);
    float e2 = expf(s_k[2] - m), e3 = expf(s_k[3] - m);
    float inv = 1.f / (e0 + e1 + e2 + e3);
    s_k[0] = e0 * inv; s_k[1] = e1 * inv; s_k[2] = e2 * inv; s_k[3] = e3 * inv;
  }
  __syncthreads();

  {
    float s = fus_b2[t];
    for (int j = 0; j < 8; ++j) s += s_h[j] * fus_w2[t * 8 + j];
    s_att2[t] = 1.f / (1.f + expf(-s));
  }
  __syncthreads();

  if (t < 2) {
    float s = 0.f;
    for (int c = 0; c < 64; ++c) s += s_att2[t * 64 + c];
    s_red[t] = s;
  }
  __syncthreads();
  if (t == 0) {
    float m = fmaxf(s_red[0], s_red[1]);
    float e1 = expf(s_red[0] - m), e2 = expf(s_red[1] - m);
    float inv = 1.f / (e1 + e2);
    s_w12[0] = e1 * inv;
    s_w12[1] = e2 * inv;
  }
  __syncthreads();

  if (t < 64) {
    o_cin[b * 64 + t]  = s_w12[0] * s_att[t];
    o_cout[b * 64 + t] = s_w12[1] * s_att[64 + t];
  }
  if (t < 9) o_sp9[b * 9 + t] = s_sp[t];
  if (t < 4) o_k4[b * 4 + t] = s_k[t];
}

// ---------------- 3) fused per-sample weight -> bf16 [b][pq][o][i] ----------------
__global__ __launch_bounds__(256) void wf_kernel(const float* __restrict__ weight,
                                                 const float* __restrict__ cin,
                                                 const float* __restrict__ cout_,
                                                 const float* __restrict__ sp9,
                                                 const float* __restrict__ k4,
                                                 ushort_t* __restrict__ wfb) {
  const int bo = blockIdx.x;
  const int b = bo >> 6, o = bo & 63;
  const float co = cout_[b * 64 + o];
  const float k0 = k4[b * 4 + 0], k1 = k4[b * 4 + 1];
  const float k2 = k4[b * 4 + 2], k3 = k4[b * 4 + 3];
  for (int idx = threadIdx.x; idx < 576; idx += 256) {
    const int pq = idx >> 6, i = idx & 63;
    const size_t wi = ((size_t)o * 64 + i) * 9 + pq;
    float s = k0 * weight[wi] + k1 * weight[36864 + wi] +
              k2 * weight[73728 + wi] + k3 * weight[110592 + wi];
    float v = co * sp9[b * 9 + pq] * cin[b * 64 + i] * s;
    wfb[((size_t)(b * 9 + pq) * 64 + o) * 64 + i] = (ushort_t)f2bf(v);
  }
}

// ---------------- 4) implicit-GEMM conv from NHWC bf16, dbuf, no conversions ----------------
// block: 512 thr (8 waves), one batch, 4 out rows x 128 cols, 64 oc.
// wave (wid): row = wid>>1, col-half = wid&1; acc = 4 f32x16 (64 AGPR).
// LDS: 2 x [px = 6*132][16 ci] bf16 (25344 B each), XOR swizzle on byte bits [6:4].
// XCD swizzle: each XCD gets 4 complete batches (wfb L2 locality).
#define TILE_BYTES 25344
__global__ __launch_bounds__(512, 4) void conv_kernel(const ushort_t* __restrict__ xb,
                                                      const ushort_t* __restrict__ wfb,
                                                      float* __restrict__ out) {
  const int wg  = blockIdx.x;
  const int swz = (wg & 7) * 128 + (wg >> 3);
  const int b   = swz >> 5;
  const int h0  = (swz & 31) << 2;
  const int tid = threadIdx.x;
  const int lane = tid & 63;
  const int wid = tid >> 6;
  const int rw    = wid >> 1;
  const int nhalf = wid & 1;
  const int l31 = lane & 31;
  const int hi  = lane >> 5;

  __shared__ __align__(16) short sx[2 * 792 * 16];   // 50688 B

  f32x16 acc00, acc01, acc10, acc11;
#pragma unroll
  for (int r = 0; r < 16; ++r) { acc00[r] = 0.f; acc01[r] = 0.f; acc10[r] = 0.f; acc11[r] = 0.f; }

  const ushort_t* wfb_b = wfb + (size_t)b * 36864;
  const ushort_t* xb_b  = xb + (size_t)b * 16384 * 64;

  // staging precompute: 1560 segs (6 rows x 130 cols x 2 octs); s = tid + 512*i
  int goff[4], loff[4];
  bool act[4], inb_[4];
#pragma unroll
  for (int i = 0; i < 4; ++i) {
    const int s = tid + i * 512;
    act[i] = s < 1560;
    const int s_ = act[i] ? s : 0;
    const int pl = s_ >> 1, oct = s_ & 1;
    const int r = pl / 130, tc = pl - r * 130;
    const int gr = h0 - 1 + r, gc = tc - 1;
    inb_[i] = act[i] && ((unsigned)gr < 128u) && ((unsigned)gc < 128u);
    goff[i] = (gr * 128 + gc) * 64 + oct * 8;
    const int px = r * 132 + tc;
    const int lg = px * 32 + oct * 16;
    loff[i] = lg ^ (((lg >> 7) & 7) << 4);
  }

  const uint4 zz = make_uint4(0u, 0u, 0u, 0u);
  uint4 st0, st1, st2, st3;

#define STAGE_LOAD(CH)                                                         \
  do {                                                                         \
    st0 = inb_[0] ? *(const uint4*)(xb_b + goff[0] + (CH) * 16) : zz;          \
    st1 = inb_[1] ? *(const uint4*)(xb_b + goff[1] + (CH) * 16) : zz;          \
    st2 = inb_[2] ? *(const uint4*)(xb_b + goff[2] + (CH) * 16) : zz;          \
    st3 = inb_[3] ? *(const uint4*)(xb_b + goff[3] + (CH) * 16) : zz;          \
  } while (0)

#define STAGE_WRITE(BUF)                                                       \
  do {                                                                         \
    *(uint4*)((char*)sx + (BUF) + loff[0]) = st0;                              \
    *(uint4*)((char*)sx + (BUF) + loff[1]) = st1;                              \
    *(uint4*)((char*)sx + (BUF) + loff[2]) = st2;                              \
    if (act[3]) *(uint4*)((char*)sx + (BUF) + loff[3]) = st3;                  \
  } while (0)

  STAGE_LOAD(0);
  STAGE_WRITE(0);
  __syncthreads();

#pragma unroll
  for (int ch = 0; ch < 4; ++ch) {
    if (ch < 3) STAGE_LOAD(ch + 1);
    const int bufb = (ch & 1) * TILE_BYTES;
    const int c0 = ch * 16;
#pragma unroll
    for (int p = 0; p < 3; ++p) {
#pragma unroll
      for (int q = 0; q < 3; ++q) {
        const int tap = p * 3 + q;
        bf16x8 af0 = *(const bf16x8*)(wfb_b + (tap * 64 + l31) * 64 + c0 + hi * 8);
        bf16x8 af1 = *(const bf16x8*)(wfb_b + (tap * 64 + 32 + l31) * 64 + c0 + hi * 8);
        const int pxa = (rw + p) * 132 + q + nhalf * 64 + l31;
        {
          const int lg = pxa * 32 + hi * 16;
          bf16x8 bf = *(const bf16x8*)((const char*)sx + bufb + (lg ^ (((lg >> 7) & 7) << 4)));
          acc00 = __builtin_amdgcn_mfma_f32_32x32x16_bf16(af0, bf, acc00, 0, 0, 0);
          acc10 = __builtin_amdgcn_mfma_f32_32x32x16_bf16(af1, bf, acc10, 0, 0, 0);
        }
        {
          const int lg = (pxa + 32) * 32 + hi * 16;
          bf16x8 bf = *(const bf16x8*)((const char*)sx + bufb + (lg ^ (((lg >> 7) & 7) << 4)));
          acc01 = __builtin_amdgcn_mfma_f32_32x32x16_bf16(af0, bf, acc01, 0, 0, 0);
          acc11 = __builtin_amdgcn_mfma_f32_32x32x16_bf16(af1, bf, acc11, 0, 0, 0);
        }
      }
    }
    if (ch < 3) {
      STAGE_WRITE(((ch + 1) & 1) * TILE_BYTES);
      __syncthreads();
    }
  }

  const int h = h0 + rw;
#define STORE_ACC(ACC, OFB, NT)                                                \
  do {                                                                         \
    const int col = nhalf * 64 + (NT) * 32 + l31;                              \
    _Pragma("unroll") for (int reg = 0; reg < 16; ++reg) {                     \
      const int o = (OFB) + (reg & 3) + ((reg >> 2) << 3) + (hi << 2);         \
      out[(((size_t)(b * 64 + o)) * 128 + h) * 128 + col] = (ACC)[reg];        \
    }                                                                          \
  } while (0)

  STORE_ACC(acc00, 0, 0);
  STORE_ACC(acc01, 0, 1);
  STORE_ACC(acc10, 32, 0);
  STORE_ACC(acc11, 32, 1);
#undef STORE_ACC
#undef STAGE_WRITE
#undef STAGE_LOAD
}

extern "C" void kernel_launch(void* const* d_in, const int* in_sizes, int n_in,
                              void* d_out, int out_size, void* d_ws, size_t ws_size,
                              hipStream_t stream) {
  const float* x      = (const float*)d_in[0];
  const float* fc_w   = (const float*)d_in[1];
  const float* ch_w   = (const float*)d_in[2];
  const float* ch_b   = (const float*)d_in[3];
  const float* f_w    = (const float*)d_in[4];
  const float* f_b    = (const float*)d_in[5];
  const float* sp_w   = (const float*)d_in[6];
  const float* sp_b   = (const float*)d_in[7];
  const float* k_w    = (const float*)d_in[8];
  const float* k_b    = (const float*)d_in[9];
  const float* fus_w1 = (const float*)d_in[10];
  const float* fus_b1 = (const float*)d_in[11];
  const float* fus_w2 = (const float*)d_in[12];
  const float* fus_b2 = (const float*)d_in[13];
  const float* weight = (const float*)d_in[14];
  float* ws  = (float*)d_ws;
  float* out = (float*)d_out;

  float* part  = ws + WP_PART;
  float* cin   = ws + WP_CIN;
  float* cout_ = ws + WP_COUT;
  float* sp9   = ws + WP_SP9;
  float* k4    = ws + WP_K4;
  ushort_t* wfb = (ushort_t*)((char*)d_ws + WB_WFB);
  ushort_t* xb  = (ushort_t*)((char*)d_ws + WB_XB);

  convert_kernel<<<1024, 256, 0, stream>>>(x, xb, part);
  att_kernel<<<32, 128, 0, stream>>>(part, 32, fc_w, ch_w, ch_b, f_w, f_b,
                                     sp_w, sp_b, k_w, k_b, fus_w1, fus_b1,
                                     fus_w2, fus_b2, cin, cout_, sp9, k4);
  wf_kernel<<<2048, 256, 0, stream>>>(weight, cin, cout_, sp9, k4, wfb);
  conv_kernel<<<1024, 512, 0, stream>>>(xb, wfb, out);
}

// Round 9
// 168.603 us; speedup vs baseline: 1.0155x; 1.0155x over previous
//
#include <hip/hip_runtime.h>
#include <math.h>
#include <stdint.h>

typedef short bf16x8 __attribute__((ext_vector_type(8)));
typedef float f32x16 __attribute__((ext_vector_type(16)));
typedef unsigned short ushort_t;

// ---------------- workspace layout ----------------
#define WP_PART 0
#define WP_CIN  65536
#define WP_COUT 67584
#define WP_SP9  69632
#define WP_K4   69920
#define WB_WFB  294912
#define WB_XB   2654208

static __device__ __forceinline__ unsigned f2bf(float f) {
  unsigned u = __builtin_bit_cast(unsigned, f);
  return (u + 0x7FFFu + ((u >> 16) & 1u)) >> 16;   // RNE
}
static __device__ __forceinline__ unsigned pk2(float a, float b) {
  return f2bf(a) | (f2bf(b) << 16);
}

// ---------------- 1) convert+pool: fp32 NCHW -> bf16 NHWC, pool partials ----------------
__global__ __launch_bounds__(256) void convert_kernel(const float* __restrict__ x,
                                                      ushort_t* __restrict__ xb,
                                                      float* __restrict__ part) {
  const int b    = blockIdx.x >> 5;
  const int band = blockIdx.x & 31;
  const int r0   = band << 2;
  const int t    = threadIdx.x;
  const int cp   = t & 31;
  const int seg  = t >> 5;

  __shared__ __align__(16) ushort_t tile[128 * 64];   // 16 KB [px][ci]
  __shared__ float red[512];

  float sa = 0.f, sb = 0.f;
  const float* xa  = x + ((size_t)(b * 64 + 2 * cp) * 16384);
  const float* xb_ = xa + 16384;

  for (int r = 0; r < 4; ++r) {
    const int gr = r0 + r;
    const int p0 = gr * 128 + seg * 16;
    float4 a0 = *(const float4*)(xa + p0);
    float4 a1 = *(const float4*)(xa + p0 + 4);
    float4 a2 = *(const float4*)(xa + p0 + 8);
    float4 a3 = *(const float4*)(xa + p0 + 12);
    float4 b0 = *(const float4*)(xb_ + p0);
    float4 b1 = *(const float4*)(xb_ + p0 + 4);
    float4 b2 = *(const float4*)(xb_ + p0 + 8);
    float4 b3 = *(const float4*)(xb_ + p0 + 12);
    sa += (a0.x + a0.y + a0.z + a0.w) + (a1.x + a1.y + a1.z + a1.w) +
          (a2.x + a2.y + a2.z + a2.w) + (a3.x + a3.y + a3.z + a3.w);
    sb += (b0.x + b0.y + b0.z + b0.w) + (b1.x + b1.y + b1.z + b1.w) +
          (b2.x + b2.y + b2.z + b2.w) + (b3.x + b3.y + b3.z + b3.w);

    unsigned* tp = (unsigned*)tile;
    const int base = seg * 16 * 32 + cp;
    tp[base +  0 * 32] = pk2(a0.x, b0.x);
    tp[base +  1 * 32] = pk2(a0.y, b0.y);
    tp[base +  2 * 32] = pk2(a0.z, b0.z);
    tp[base +  3 * 32] = pk2(a0.w, b0.w);
    tp[base +  4 * 32] = pk2(a1.x, b1.x);
    tp[base +  5 * 32] = pk2(a1.y, b1.y);
    tp[base +  6 * 32] = pk2(a1.z, b1.z);
    tp[base +  7 * 32] = pk2(a1.w, b1.w);
    tp[base +  8 * 32] = pk2(a2.x, b2.x);
    tp[base +  9 * 32] = pk2(a2.y, b2.y);
    tp[base + 10 * 32] = pk2(a2.z, b2.z);
    tp[base + 11 * 32] = pk2(a2.w, b2.w);
    tp[base + 12 * 32] = pk2(a3.x, b3.x);
    tp[base + 13 * 32] = pk2(a3.y, b3.y);
    tp[base + 14 * 32] = pk2(a3.z, b3.z);
    tp[base + 15 * 32] = pk2(a3.w, b3.w);
    __syncthreads();

    ushort_t* xbr = xb + ((size_t)(b * 16384 + gr * 128)) * 64;
#pragma unroll
    for (int i = 0; i < 4; ++i) {
      const int s = i * 256 + t;
      uint4 v = *(const uint4*)((const char*)tile + s * 16);
      *(uint4*)(xbr + (size_t)s * 8) = v;
    }
    __syncthreads();
  }

  red[t] = sa;
  red[256 + t] = sb;
  __syncthreads();
  if (t < 64) {
    const int ci = t;
    const int base = (ci & 1) * 256 + (ci >> 1);
    float s = 0.f;
#pragma unroll
    for (int k = 0; k < 8; ++k) s += red[base + k * 32];
    part[((size_t)b * 32 + band) * 64 + ci] = s;
  }
}

// ---------------- 2) attention chain, one block per batch ----------------
__global__ __launch_bounds__(128) void att_kernel(
    const float* __restrict__ pin, int n_part,
    const float* __restrict__ fc_w, const float* __restrict__ ch_w, const float* __restrict__ ch_b,
    const float* __restrict__ f_w,  const float* __restrict__ f_b,
    const float* __restrict__ sp_w, const float* __restrict__ sp_b,
    const float* __restrict__ k_w,  const float* __restrict__ k_b,
    const float* __restrict__ fus_w1, const float* __restrict__ fus_b1,
    const float* __restrict__ fus_w2, const float* __restrict__ fus_b2,
    float* __restrict__ o_cin, float* __restrict__ o_cout,
    float* __restrict__ o_sp9, float* __restrict__ o_k4) {
  const int b = blockIdx.x;
  const int t = threadIdx.x;
  __shared__ float s_pool[64], s_a[16], s_att[128], s_sp[9], s_k[4], s_h[8],
      s_att2[128], s_red[2], s_w12[2];

  if (t < 64) {
    float s = 0.f;
    for (int g = 0; g < n_part; ++g) s += pin[((size_t)b * n_part + g) * 64 + t];
    s_pool[t] = s * (1.f / 16384.f);
  }
  __syncthreads();

  if (t < 16) {
    float s = 0.f;
    for (int c = 0; c < 64; ++c) s += s_pool[c] * fc_w[t * 64 + c];
    s_a[t] = fmaxf(s, 0.f);
  }
  __syncthreads();

  if (t < 64) {
    float s = ch_b[t];
    for (int j = 0; j < 16; ++j) s += s_a[j] * ch_w[t * 16 + j];
    s_att[t] = 1.f / (1.f + expf(-s));
  } else {
    const int o = t - 64;
    float s = f_b[o];
    for (int j = 0; j < 16; ++j) s += s_a[j] * f_w[o * 16 + j];
    s_att[t] = 1.f / (1.f + expf(-s));
  }
  if (t < 9) {
    float s = sp_b[t];
    for (int j = 0; j < 16; ++j) s += s_a[j] * sp_w[t * 16 + j];
    s_sp[t] = 1.f / (1.f + expf(-s));
  }
  if (t < 4) {
    float s = k_b[t];
    for (int j = 0; j < 16; ++j) s += s_a[j] * k_w[t * 16 + j];
    s_k[t] = s;
  }
  __syncthreads();

  if (t < 8) {
    float s = fus_b1[t];
    for (int c = 0; c < 128; ++c) s += s_att[c] * fus_w1[t * 128 + c];
    s_h[t] = fmaxf(s, 0.f);
  }
  if (t == 127) {
    float m = fmaxf(fmaxf(s_k[0], s_k[1]), fmaxf(s_k[2], s_k[3]));
    float e0 = expf(s_k[0] - m), e1 = expf(s_k[1] - m);
    float e2 = expf(s_k[2] - m), e3 = expf(s_k[3] - m);
    float inv = 1.f / (e0 + e1 + e2 + e3);
    s_k[0] = e0 * inv; s_k[1] = e1 * inv; s_k[2] = e2 * inv; s_k[3] = e3 * inv;
  }
  __syncthreads();

  {
    float s = fus_b2[t];
    for (int j = 0; j < 8; ++j) s += s_h[j] * fus_w2[t * 8 + j];
    s_att2[t] = 1.f / (1.f + expf(-s));
  }
  __syncthreads();

  if (t < 2) {
    float s = 0.f;
    for (int c = 0; c < 64; ++c) s += s_att2[t * 64 + c];
    s_red[t] = s;
  }
  __syncthreads();
  if (t == 0) {
    float m = fmaxf(s_red[0], s_red[1]);
    float e1 = expf(s_red[0] - m), e2 = expf(s_red[1] - m);
    float inv = 1.f / (e1 + e2);
    s_w12[0] = e1 * inv;
    s_w12[1] = e2 * inv;
  }
  __syncthreads();

  if (t < 64) {
    o_cin[b * 64 + t]  = s_w12[0] * s_att[t];
    o_cout[b * 64 + t] = s_w12[1] * s_att[64 + t];
  }
  if (t < 9) o_sp9[b * 9 + t] = s_sp[t];
  if (t < 4) o_k4[b * 4 + t] = s_k[t];
}

// ---------------- 3) fused per-sample weight -> bf16 [b][pq][o][i] ----------------
__global__ __launch_bounds__(256) void wf_kernel(const float* __restrict__ weight,
                                                 const float* __restrict__ cin,
                                                 const float* __restrict__ cout_,
                                                 const float* __restrict__ sp9,
                                                 const float* __restrict__ k4,
                                                 ushort_t* __restrict__ wfb) {
  const int bo = blockIdx.x;
  const int b = bo >> 6, o = bo & 63;
  const float co = cout_[b * 64 + o];
  const float k0 = k4[b * 4 + 0], k1 = k4[b * 4 + 1];
  const float k2 = k4[b * 4 + 2], k3 = k4[b * 4 + 3];
  for (int idx = threadIdx.x; idx < 576; idx += 256) {
    const int pq = idx >> 6, i = idx & 63;
    const size_t wi = ((size_t)o * 64 + i) * 9 + pq;
    float s = k0 * weight[wi] + k1 * weight[36864 + wi] +
              k2 * weight[73728 + wi] + k3 * weight[110592 + wi];
    float v = co * sp9[b * 9 + pq] * cin[b * 64 + i] * s;
    wfb[((size_t)(b * 9 + pq) * 64 + o) * 64 + i] = (ushort_t)f2bf(v);
  }
}

// ---------------- 4) conv: 2-row blocks, 32-AGPR waves, tap-pipelined ----------------
// block: 512 thr (8 waves), one batch, 2 out rows x 128 cols, 64 oc.
// wave wid: rw = wid>>2 (row), of = (wid>>1)&1 (oc half), nh = wid&1 (col half).
// acc = 2 x f32x16 (32 AGPR). af + bf software-pipelined one tap ahead.
// LDS: 2 x [px = 4*132][16 ci] bf16 = 33792 B, XOR swizzle byte bits [6:4].
// staging: 1040 segs (4 rows x 130 cols x 2 octs) = s:tid, tid+512, tid+1024(tid<16)
#define TILE_BYTES 16896
__global__ __launch_bounds__(512, 4) void conv_kernel(const ushort_t* __restrict__ xb,
                                                      const ushort_t* __restrict__ wfb,
                                                      float* __restrict__ out) {
  const int wg  = blockIdx.x;
  const int swz = (wg & 7) * 256 + (wg >> 3);
  const int b   = swz >> 6;
  const int h0  = (swz & 63) << 1;
  const int tid = threadIdx.x;
  const int lane = tid & 63;
  const int wid = tid >> 6;
  const int rw   = wid >> 2;
  const int of32 = ((wid >> 1) & 1) << 5;
  const int nh   = wid & 1;
  const int l31 = lane & 31;
  const int hi  = lane >> 5;

  __shared__ __align__(16) short sx[2 * 528 * 16];   // 33792 B

  f32x16 acc0, acc1;
#pragma unroll
  for (int r = 0; r < 16; ++r) { acc0[r] = 0.f; acc1[r] = 0.f; }

  const ushort_t* wfb_b = wfb + (size_t)b * 36864;
  const ushort_t* xb_b  = xb + (size_t)b * 16384 * 64;

  // staging slot precompute (3 slots)
  int goff0, goff1, goff2, loff0, loff1, loff2;
  bool inb0, inb1, inb2;
  const bool act2 = tid < 16;
  {
    const int s = tid;
    const int oct = s & 1, pl = s >> 1;
    const int r = pl / 130, tc = pl - r * 130;
    const int gr = h0 - 1 + r, gc = tc - 1;
    inb0 = ((unsigned)gr < 128u) && ((unsigned)gc < 128u);
    goff0 = (gr * 128 + gc) * 64 + oct * 8;
    const int lg = (r * 132 + tc) * 32 + oct * 16;
    loff0 = lg ^ ((((lg >> 7) & 7)) << 4);
  }
  {
    const int s = tid + 512;
    const int oct = s & 1, pl = s >> 1;
    const int r = pl / 130, tc = pl - r * 130;
    const int gr = h0 - 1 + r, gc = tc - 1;
    inb1 = ((unsigned)gr < 128u) && ((unsigned)gc < 128u);
    goff1 = (gr * 128 + gc) * 64 + oct * 8;
    const int lg = (r * 132 + tc) * 32 + oct * 16;
    loff1 = lg ^ ((((lg >> 7) & 7)) << 4);
  }
  {
    const int s = act2 ? (tid + 1024) : 0;
    const int oct = s & 1, pl = s >> 1;
    const int r = pl / 130, tc = pl - r * 130;
    const int gr = h0 - 1 + r, gc = tc - 1;
    inb2 = act2 && ((unsigned)gr < 128u) && ((unsigned)gc < 128u);
    goff2 = (gr * 128 + gc) * 64 + oct * 8;
    const int lg = (r * 132 + tc) * 32 + oct * 16;
    loff2 = lg ^ ((((lg >> 7) & 7)) << 4);
  }

  const uint4 zz = make_uint4(0u, 0u, 0u, 0u);
  uint4 st0, st1, st2;

#define STAGE_LOAD(CH)                                                   \
  do {                                                                   \
    st0 = inb0 ? *(const uint4*)(xb_b + goff0 + (CH) * 16) : zz;         \
    st1 = inb1 ? *(const uint4*)(xb_b + goff1 + (CH) * 16) : zz;         \
    st2 = inb2 ? *(const uint4*)(xb_b + goff2 + (CH) * 16) : zz;         \
  } while (0)

#define STAGE_WRITE(BUF)                                                 \
  do {                                                                   \
    *(uint4*)((char*)sx + (BUF) + loff0) = st0;                          \
    *(uint4*)((char*)sx + (BUF) + loff1) = st1;                          \
    if (act2) *(uint4*)((char*)sx + (BUF) + loff2) = st2;                \
  } while (0)

  // B-frag LDS read: tap t (p=t/3,q=t%3), nt in {0,1}
  const int colbase = nh * 64 + l31;
#define BX(BUFB, T, NT)                                                           \
  (*(const bf16x8*)((const char*)sx + (BUFB) +                                    \
    ((((rw + (T) / 3) * 132 + (T) % 3 + colbase + (NT) * 32) * 32 + hi * 16) ^    \
     (((((rw + (T) / 3) * 132 + (T) % 3 + colbase + (NT) * 32) * 32 + hi * 16) >> 7) & 7) << 4)))

#define AF(T, C0) \
  (*(const bf16x8*)(wfb_b + ((T) * 64 + of32 + l31) * 64 + (C0) + hi * 8))

  STAGE_LOAD(0);
  STAGE_WRITE(0);
  __syncthreads();

#pragma unroll
  for (int ch = 0; ch < 4; ++ch) {
    if (ch < 3) STAGE_LOAD(ch + 1);
    const int bufb = (ch & 1) * TILE_BYTES;
    const int c0 = ch * 16;

    bf16x8 afA = AF(0, c0);
    bf16x8 b0A = BX(bufb, 0, 0);
    bf16x8 b1A = BX(bufb, 0, 1);
#pragma unroll
    for (int t = 0; t < 9; ++t) {
      bf16x8 afB, b0B, b1B;
      if (t < 8) {
        afB = AF(t + 1, c0);
        b0B = BX(bufb, t + 1, 0);
        b1B = BX(bufb, t + 1, 1);
      }
      acc0 = __builtin_amdgcn_mfma_f32_32x32x16_bf16(afA, b0A, acc0, 0, 0, 0);
      acc1 = __builtin_amdgcn_mfma_f32_32x32x16_bf16(afA, b1A, acc1, 0, 0, 0);
      if (t < 8) { afA = afB; b0A = b0B; b1A = b1B; }
    }

    if (ch < 3) {
      STAGE_WRITE(((ch + 1) & 1) * TILE_BYTES);
      __syncthreads();
    }
  }

  const int h = h0 + rw;
#define STORE_ACC(ACC, NT)                                                     \
  do {                                                                         \
    const int col = nh * 64 + (NT) * 32 + l31;                                 \
    _Pragma("unroll") for (int reg = 0; reg < 16; ++reg) {                     \
      const int o = of32 + (reg & 3) + ((reg >> 2) << 3) + (hi << 2);          \
      out[(((size_t)(b * 64 + o)) * 128 + h) * 128 + col] = (ACC)[reg];        \
    }                                                                          \
  } while (0)

  STORE_ACC(acc0, 0);
  STORE_ACC(acc1, 1);
#undef STORE_ACC
#undef AF
#undef BX
#undef STAGE_WRITE
#undef STAGE_LOAD
}

extern "C" void kernel_launch(void* const* d_in, const int* in_sizes, int n_in,
                              void* d_out, int out_size, void* d_ws, size_t ws_size,
                              hipStream_t stream) {
  const float* x      = (const float*)d_in[0];
  const float* fc_w   = (const float*)d_in[1];
  const float* ch_w   = (const float*)d_in[2];
  const float* ch_b   = (const float*)d_in[3];
  const float* f_w    = (const float*)d_in[4];
  const float* f_b    = (const float*)d_in[5];
  const float* sp_w   = (const float*)d_in[6];
  const float* sp_b   = (const float*)d_in[7];
  const float* k_w    = (const float*)d_in[8];
  const float* k_b    = (const float*)d_in[9];
  const float* fus_w1 = (const float*)d_in[10];
  const float* fus_b1 = (const float*)d_in[11];
  const float* fus_w2 = (const float*)d_in[12];
  const float* fus_b2 = (const float*)d_in[13];
  const float* weight = (const float*)d_in[14];
  float* ws  = (float*)d_ws;
  float* out = (float*)d_out;

  float* part  = ws + WP_PART;
  float* cin   = ws + WP_CIN;
  float* cout_ = ws + WP_COUT;
  float* sp9   = ws + WP_SP9;
  float* k4    = ws + WP_K4;
  ushort_t* wfb = (ushort_t*)((char*)d_ws + WB_WFB);
  ushort_t* xb  = (ushort_t*)((char*)d_ws + WB_XB);

  convert_kernel<<<1024, 256, 0, stream>>>(x, xb, part);
  att_kernel<<<32, 128, 0, stream>>>(part, 32, fc_w, ch_w, ch_b, f_w, f_b,
                                     sp_w, sp_b, k_w, k_b, fus_w1, fus_b1,
                                     fus_w2, fus_b2, cin, cout_, sp9, k4);
  wf_kernel<<<2048, 256, 0, stream>>>(weight, cin, cout_, sp9, k4, wfb);
  conv_kernel<<<2048, 512, 0, stream>>>(xb, wfb, out);
}